// Round 1
// baseline (1738.794 us; speedup 1.0000x reference)
//
#include <hip/hip_runtime.h>
#include <hip/hip_bf16.h>
#include <math.h>

#define B_    8
#define S_    8192
#define DIN_  512
#define DH_   512
#define HN_   4
#define HD_   128
#define CHUNK_ 16
#define NC_   (S_/CHUNK_)
#define NTOK  (B_*S_)

__device__ __forceinline__ float sigmoidf_(float z) {
    return 1.0f / (1.0f + expf(-z));
}

// ---------------------------------------------------------------------------
// Kernel 1: xp = x @ W_in^T ; LayerNorm ; gates ; writes
//   a_buf[bs*4+n]   = tanh(eig_raw[n]) * sigmoid(gate_n)
//   bvec[bs*512+c]  = sigmoid(gate_{4+n(c)}) * xn[c]        (bvec lives in d_out)
// Block: 256 threads, 16 tokens. Per thread: 4 tokens (wave-local) x 8 cols
// (c = lane + 64*j). W tile staged in LDS with XOR swizzle for conflict-free
// ds_read_b128.
// ---------------------------------------------------------------------------
__global__ __launch_bounds__(256) void k1_gemm_ln_gates(
    const float* __restrict__ x, const float* __restrict__ Win,
    const float* __restrict__ gamma, const float* __restrict__ beta,
    const float* __restrict__ Wg, const float* __restrict__ bg,
    const float* __restrict__ eig_raw,
    float* __restrict__ bvec, float* __restrict__ a_buf)
{
    __shared__ float xs[16*512];    // 32 KB: 16 token rows, full K
    __shared__ float wsm[512*16];   // 32 KB: [c][kk] xor-swizzled
    const int tid = threadIdx.x;
    const long t0 = (long)blockIdx.x * 16;

    {   // load x tile, coalesced float4
        const float4* xg = (const float4*)(x + t0*DIN_);
        float4* xl = (float4*)xs;
        #pragma unroll
        for (int i = 0; i < 8; ++i) xl[tid + i*256] = xg[tid + i*256];
    }

    const int l = tid & 63;   // lane
    const int w = tid >> 6;   // wave = token group

    float acc[4][8];
    #pragma unroll
    for (int m = 0; m < 4; ++m)
        #pragma unroll
        for (int j = 0; j < 8; ++j) acc[m][j] = 0.f;

    for (int kt = 0; kt < 512; kt += 16) {
        __syncthreads();
        // stage W tile: Ws[c][kk], kk0 xor-swizzled by ((c>>1)&3)<<2
        #pragma unroll
        for (int i = 0; i < 8; ++i) {
            int f4i = tid + i*256;            // 0..2047
            int c   = f4i >> 2;
            int kk0 = (f4i & 3) << 2;
            float4 wv = *(const float4*)&Win[(long)c*DIN_ + kt + kk0];
            int kks = kk0 ^ (((c >> 1) & 3) << 2);
            *(float4*)&wsm[c*16 + kks] = wv;
        }
        __syncthreads();
        #pragma unroll
        for (int kk4 = 0; kk4 < 4; ++kk4) {
            int kk0 = kk4 << 2;
            float4 xv[4];
            #pragma unroll
            for (int m = 0; m < 4; ++m)
                xv[m] = *(const float4*)&xs[(w*4+m)*512 + kt + kk0];
            #pragma unroll
            for (int j = 0; j < 8; ++j) {
                int c = l + (j << 6);
                int kks = kk0 ^ (((c >> 1) & 3) << 2);
                float4 wv = *(const float4*)&wsm[c*16 + kks];
                #pragma unroll
                for (int m = 0; m < 4; ++m) {
                    acc[m][j] = fmaf(xv[m].x, wv.x, acc[m][j]);
                    acc[m][j] = fmaf(xv[m].y, wv.y, acc[m][j]);
                    acc[m][j] = fmaf(xv[m].z, wv.z, acc[m][j]);
                    acc[m][j] = fmaf(xv[m].w, wv.w, acc[m][j]);
                }
            }
        }
    }

    // ---- LayerNorm + gates (per token, wave-wide butterflies) ----
    float gam[8], bet[8];
    #pragma unroll
    for (int j = 0; j < 8; ++j) { gam[j] = gamma[l+(j<<6)]; bet[j] = beta[l+(j<<6)]; }
    float eig[4], bgl[8];
    #pragma unroll
    for (int n = 0; n < 4; ++n) eig[n] = tanhf(eig_raw[n]);
    #pragma unroll
    for (int g = 0; g < 8; ++g) bgl[g] = bg[g];

    #pragma unroll
    for (int m = 0; m < 4; ++m) {
        float s1 = 0.f, s2 = 0.f;
        #pragma unroll
        for (int j = 0; j < 8; ++j) { float v = acc[m][j]; s1 += v; s2 += v*v; }
        #pragma unroll
        for (int o = 32; o; o >>= 1) { s1 += __shfl_xor(s1, o, 64); s2 += __shfl_xor(s2, o, 64); }
        float mean = s1 * (1.f/512.f);
        float var  = s2 * (1.f/512.f) - mean*mean;
        float rstd = 1.0f / sqrtf(var + 1e-5f);

        float xn[8];
        #pragma unroll
        for (int j = 0; j < 8; ++j) xn[j] = (acc[m][j] - mean) * rstd * gam[j] + bet[j];

        float gt[8];
        #pragma unroll
        for (int g = 0; g < 8; ++g) {
            float p = 0.f;
            #pragma unroll
            for (int j = 0; j < 8; ++j) p = fmaf(xn[j], Wg[g*DH_ + l + (j<<6)], p);
            #pragma unroll
            for (int o = 32; o; o >>= 1) p += __shfl_xor(p, o, 64);
            gt[g] = p + bgl[g];
        }

        long bs = t0 + w*4 + m;
        if (l < 4) a_buf[bs*4 + l] = eig[l] * sigmoidf_(gt[l]);
        float btg[4];
        #pragma unroll
        for (int n = 0; n < 4; ++n) btg[n] = sigmoidf_(gt[4+n]);
        #pragma unroll
        for (int j = 0; j < 8; ++j) {
            int c = l + (j << 6);
            bvec[bs*512 + c] = btg[c >> 7] * xn[j];
        }
    }
}

// ---------------------------------------------------------------------------
// Kernel 2 (phase A): per (b, chunk): cumprod p_t, q_t = max(p_t,1e-6),
// B0_t = q_t * sum_{tau<=t} b_tau/q_tau  (in place over bvec), p -> p_buf.
// ---------------------------------------------------------------------------
__global__ __launch_bounds__(256) void k2_phaseA(
    const float* __restrict__ a_buf, float* __restrict__ p_buf,
    float* __restrict__ bvec)
{
    const int blk = blockIdx.x;
    const int b = blk >> 9, ch = blk & 511;
    const long base_s = (long)b*S_ + (long)ch*CHUNK_;
    __shared__ float qs[CHUNK_][HN_];
    const int tid = threadIdx.x;

    if (tid < HN_) {
        const int n = tid;
        float p = 1.f;
        for (int t = 0; t < CHUNK_; ++t) {
            p *= a_buf[(base_s + t)*HN_ + n];
            p_buf[(base_s + t)*HN_ + n] = p;
            qs[t][n] = fmaxf(p, 1e-6f);
        }
    }
    __syncthreads();

    #pragma unroll
    for (int cc = 0; cc < 2; ++cc) {
        const int c = tid + cc*256;
        const int n = c >> 7;
        float s = 0.f;
        long idx = base_s*DH_ + c;
        #pragma unroll
        for (int t = 0; t < CHUNK_; ++t, idx += DH_) {
            float bb = bvec[idx];
            float q  = qs[t][n];
            s += bb / q;
            bvec[idx] = q * s;
        }
    }
}

// ---------------------------------------------------------------------------
// Kernel 3 (phase B): sequential scan over 512 chunk carries.
// 4096 independent (b, n, d) lanes. Writes h0 per chunk + final h_last.
// ---------------------------------------------------------------------------
__global__ __launch_bounds__(256) void k3_scan(
    const float* __restrict__ p_buf, const float* __restrict__ bvec,
    const float* __restrict__ h_in, float* __restrict__ h0_buf,
    float* __restrict__ h_last)
{
    const int tid = blockIdx.x*blockDim.x + threadIdx.x; // 0..4095
    const int b = tid >> 9, c = tid & 511, n = c >> 7;
    float h = h_in[b*DH_ + c];
    for (int ch = 0; ch < NC_; ++ch) {
        h0_buf[((long)(b*NC_ + ch))*DH_ + c] = h;
        long sE = (long)b*S_ + (long)ch*CHUNK_ + (CHUNK_-1);
        float p15 = p_buf[sE*HN_ + n];
        float B15 = bvec[sE*DH_ + c];
        h = fmaf(p15, h, B15);
    }
    h_last[b*DH_ + c] = h;
}

// ---------------------------------------------------------------------------
// Kernel 4 (phase C): h_all = p_t * h0_chunk + B0_t   (in place over bvec)
// ---------------------------------------------------------------------------
__global__ __launch_bounds__(256) void k4_phaseC(
    const float* __restrict__ p_buf, const float* __restrict__ h0_buf,
    float* __restrict__ hall)
{
    const long total = (long)NTOK*DH_/4;
    for (long i = (long)blockIdx.x*blockDim.x + threadIdx.x; i < total;
         i += (long)gridDim.x*blockDim.x) {
        long e = i*4;
        int c = (int)(e & 511); int n = c >> 7;
        long bs = e >> 9;
        int b = (int)(bs >> 13); int s = (int)(bs & 8191);
        float p = p_buf[bs*HN_ + n];
        float4 h0 = *(const float4*)&h0_buf[((long)(b*NC_ + (s >> 4)))*DH_ + c];
        float4 v  = *(float4*)&hall[e];
        v.x = fmaf(p, h0.x, v.x);
        v.y = fmaf(p, h0.y, v.y);
        v.z = fmaf(p, h0.z, v.z);
        v.w = fmaf(p, h0.w, v.w);
        *(float4*)&hall[e] = v;
    }
}

// ---------------------------------------------------------------------------
// Kernel 5: out = h_all @ W_out^T, IN PLACE per row of d_out.
// Same GEMM structure as k1 (rows staged to LDS first, so in-place is safe).
// ---------------------------------------------------------------------------
__global__ __launch_bounds__(256) void k5_out_gemm(
    const float* __restrict__ Wout, float* __restrict__ io)
{
    __shared__ float xs[16*512];
    __shared__ float wsm[512*16];
    const int tid = threadIdx.x;
    const long t0 = (long)blockIdx.x * 16;
    {
        const float4* xg = (const float4*)(io + t0*DH_);
        float4* xl = (float4*)xs;
        #pragma unroll
        for (int i = 0; i < 8; ++i) xl[tid + i*256] = xg[tid + i*256];
    }
    const int l = tid & 63, w = tid >> 6;
    float acc[4][8];
    #pragma unroll
    for (int m = 0; m < 4; ++m)
        #pragma unroll
        for (int j = 0; j < 8; ++j) acc[m][j] = 0.f;

    for (int kt = 0; kt < 512; kt += 16) {
        __syncthreads();
        #pragma unroll
        for (int i = 0; i < 8; ++i) {
            int f4i = tid + i*256;
            int c   = f4i >> 2;
            int kk0 = (f4i & 3) << 2;
            float4 wv = *(const float4*)&Wout[(long)c*DH_ + kt + kk0];
            int kks = kk0 ^ (((c >> 1) & 3) << 2);
            *(float4*)&wsm[c*16 + kks] = wv;
        }
        __syncthreads();
        #pragma unroll
        for (int kk4 = 0; kk4 < 4; ++kk4) {
            int kk0 = kk4 << 2;
            float4 xv[4];
            #pragma unroll
            for (int m = 0; m < 4; ++m)
                xv[m] = *(const float4*)&xs[(w*4+m)*512 + kt + kk0];
            #pragma unroll
            for (int j = 0; j < 8; ++j) {
                int c = l + (j << 6);
                int kks = kk0 ^ (((c >> 1) & 3) << 2);
                float4 wv = *(const float4*)&wsm[c*16 + kks];
                #pragma unroll
                for (int m = 0; m < 4; ++m) {
                    acc[m][j] = fmaf(xv[m].x, wv.x, acc[m][j]);
                    acc[m][j] = fmaf(xv[m].y, wv.y, acc[m][j]);
                    acc[m][j] = fmaf(xv[m].z, wv.z, acc[m][j]);
                    acc[m][j] = fmaf(xv[m].w, wv.w, acc[m][j]);
                }
            }
        }
    }
    // all data needed was staged in LDS; safe to overwrite our rows
    #pragma unroll
    for (int m = 0; m < 4; ++m) {
        long bs = t0 + w*4 + m;
        #pragma unroll
        for (int j = 0; j < 8; ++j)
            io[bs*DH_ + l + (j << 6)] = acc[m][j];
    }
}

extern "C" void kernel_launch(void* const* d_in, const int* in_sizes, int n_in,
                              void* d_out, int out_size, void* d_ws, size_t ws_size,
                              hipStream_t stream) {
    const float* x       = (const float*)d_in[0];
    const float* h       = (const float*)d_in[1];
    const float* Win     = (const float*)d_in[2];
    const float* gamma   = (const float*)d_in[3];
    const float* beta    = (const float*)d_in[4];
    const float* Wg      = (const float*)d_in[5];
    const float* bg      = (const float*)d_in[6];
    const float* eig_raw = (const float*)d_in[7];
    const float* Wout    = (const float*)d_in[8];

    float* out    = (float*)d_out;
    float* bvec   = out;                          // reused: bvec -> B0 -> h_all -> out
    float* h_last = out + (long)NTOK*DH_;         // tail of d_out

    float* ws     = (float*)d_ws;
    float* a_buf  = ws;                           // B*S*HN   = 262144 f
    float* p_buf  = ws + (long)NTOK*HN_;          // B*S*HN   = 262144 f
    float* h0_buf = ws + 2L*NTOK*HN_;             // B*NC*DH  = 2097152 f  (10.5 MB total)

    k1_gemm_ln_gates<<<NTOK/16, 256, 0, stream>>>(x, Win, gamma, beta, Wg, bg,
                                                  eig_raw, bvec, a_buf);
    k2_phaseA<<<B_*NC_, 256, 0, stream>>>(a_buf, p_buf, bvec);
    k3_scan<<<16, 256, 0, stream>>>(p_buf, bvec, h, h0_buf, h_last);
    k4_phaseC<<<2048, 256, 0, stream>>>(p_buf, h0_buf, bvec);
    k5_out_gemm<<<NTOK/16, 256, 0, stream>>>(Wout, bvec);
}

// Round 2
// 319.417 us; speedup vs baseline: 5.4437x; 5.4437x over previous
//
#include <hip/hip_runtime.h>
#include <hip/hip_bf16.h>
#include <math.h>

#define B_    8
#define S_    8192
#define DIN_  512
#define DH_   512
#define HN_   4
#define HD_   128
#define CHUNK_ 16
#define NC_   (S_/CHUNK_)
#define NTOK  (B_*S_)

typedef __bf16 bf16x8 __attribute__((ext_vector_type(8)));
typedef float  f32x4  __attribute__((ext_vector_type(4)));

__device__ __forceinline__ float sigmoidf_(float z) { return 1.0f / (1.0f + expf(-z)); }

__device__ __forceinline__ unsigned short f2bf(float f) {
    union { float f; unsigned u; } v; v.f = f;
    unsigned u = v.u;
    u += 0x7fffu + ((u >> 16) & 1u);   // RNE
    return (unsigned short)(u >> 16);
}
__device__ __forceinline__ unsigned long long pack4bf(float4 a) {
    return (unsigned long long)f2bf(a.x)
         | ((unsigned long long)f2bf(a.y) << 16)
         | ((unsigned long long)f2bf(a.z) << 32)
         | ((unsigned long long)f2bf(a.w) << 48);
}
__device__ __forceinline__ void gload_lds16(const void* g, void* lds) {
    __builtin_amdgcn_global_load_lds(
        (const __attribute__((address_space(1))) unsigned int*)g,
        (__attribute__((address_space(3))) unsigned int*)lds, 16, 0, 0);
}

// ---------------------------------------------------------------------------
// k0: convert W_in / W_out f32 -> bf16, pre-permuted to the GEMM's LDS layout:
//   Wre[kt16][o][c][j] = W[c][kt16*32 + o*8 + j]   (ushort)
// so each K-step's B-tile stage is a contiguous 32KB copy via global_load_lds.
// ---------------------------------------------------------------------------
__global__ __launch_bounds__(256) void k0_convert(
    const float* __restrict__ Win, const float* __restrict__ Wout,
    unsigned short* __restrict__ WreA, unsigned short* __restrict__ WreB)
{
    int idx = blockIdx.x * 256 + threadIdx.x;          // 262144 total
    if (idx < 262144) {
        int c = idx >> 9, k = idx & 511;
        int dst = ((k >> 5) << 14) + (((k >> 3) & 3) << 12) + (c << 3) + (k & 7);
        WreA[dst] = f2bf(Win[idx]);
        WreB[dst] = f2bf(Wout[idx]);
    }
}

// ---------------------------------------------------------------------------
// gemm_rows: out[t][c] = sum_k A[t][k] * W[c][k], M-tiled 32 rows/block,
// whole row N=512 per block (in-place safe: block writes only rows it owns,
// after all K reads). 256 thr = 4 waves (1x4), per-wave 32x128 via
// mfma_f32_16x16x32_bf16, acc[2][8].
// FUSED: A[t][k] = bvec[t][k] + p_buf[t][k>>7] * h0_buf[t>>4][k]  (phase C)
// ---------------------------------------------------------------------------
template<bool FUSED>
__global__ __launch_bounds__(256) void gemm_rows(
    const float* Asrc,                         // aliases out when FUSED
    const unsigned short* __restrict__ Wre,
    const float* __restrict__ p_buf,
    const float* __restrict__ h0_buf,
    float* out)
{
    __shared__ alignas(16) unsigned short Alds[4][32][8];    // 2 KB, octet-major
    __shared__ alignas(16) unsigned short Blds[4][512][8];   // 32 KB, octet-major

    const int tid = threadIdx.x;
    const int l = tid & 63, wid = tid >> 6;    // wave col = wid
    const int og = l >> 4, lr = l & 15;
    const long t0 = (long)blockIdx.x * 32;

    f32x4 acc[2][8];
    #pragma unroll
    for (int m = 0; m < 2; ++m)
        #pragma unroll
        for (int n = 0; n < 8; ++n) acc[m][n] = (f32x4)(0.f);

    const int arow = tid >> 3, aq = tid & 7;
    const long atok = t0 + arow;

    for (int kt16 = 0; kt16 < 16; ++kt16) {
        const int kt = kt16 << 5;
        __syncthreads();   // previous compute done before overwriting LDS
        // --- stage B: contiguous 32KB copy, 8 x 16B per thread, direct-to-LDS
        const char* gW = (const char*)Wre + ((long)kt16 << 15);
        char* lB = (char*)&Blds[0][0][0] + (wid << 10);
        #pragma unroll
        for (int i = 0; i < 8; ++i)
            gload_lds16(gW + (i << 12) + (wid << 10) + (l << 4), lB + (i << 12));
        // --- stage A: 4 f32 -> 4 bf16 per thread
        float4 av;
        if (!FUSED) {
            av = *(const float4*)&Asrc[atok * 512 + kt + (aq << 2)];
        } else {
            const float4 bv = *(const float4*)&Asrc[atok * 512 + kt + (aq << 2)];
            const float4 h0 = *(const float4*)&h0_buf[(atok >> 4) * 512 + kt + (aq << 2)];
            const float p  = p_buf[(atok << 2) + (kt >> 7)];
            av.x = fmaf(p, h0.x, bv.x);
            av.y = fmaf(p, h0.y, bv.y);
            av.z = fmaf(p, h0.z, bv.z);
            av.w = fmaf(p, h0.w, bv.w);
        }
        *reinterpret_cast<unsigned long long*>(&Alds[aq >> 1][arow][(aq & 1) << 2]) = pack4bf(av);
        __syncthreads();   // stage complete (drains vmcnt + lgkmcnt)

        // --- compute: frag loads (conflict-free b128) + 16 MFMA
        bf16x8 afr[2], bfr[8];
        #pragma unroll
        for (int m = 0; m < 2; ++m)
            afr[m] = *reinterpret_cast<const bf16x8*>(&Alds[og][(m << 4) + lr][0]);
        #pragma unroll
        for (int n = 0; n < 8; ++n)
            bfr[n] = *reinterpret_cast<const bf16x8*>(&Blds[og][(wid << 7) + (n << 4) + lr][0]);
        #pragma unroll
        for (int m = 0; m < 2; ++m)
            #pragma unroll
            for (int n = 0; n < 8; ++n)
                acc[m][n] = __builtin_amdgcn_mfma_f32_16x16x32_bf16(afr[m], bfr[n], acc[m][n], 0, 0, 0);
    }

    // --- epilogue: C/D layout col=lane&15, row=(lane>>4)*4+reg
    #pragma unroll
    for (int m = 0; m < 2; ++m) {
        const long rb = t0 + (m << 4) + (og << 2);
        #pragma unroll
        for (int n = 0; n < 8; ++n) {
            const int col = (wid << 7) + (n << 4) + lr;
            #pragma unroll
            for (int j = 0; j < 4; ++j)
                out[(rb + j) * 512 + col] = acc[m][n][j];
        }
    }
}

// ---------------------------------------------------------------------------
// k_ln_gates: per token (1 wave each): LayerNorm over 512, 8 gate dots,
// in-place xp -> bvec, a_buf write. Memory-bound.
// ---------------------------------------------------------------------------
__global__ __launch_bounds__(256) void k_ln_gates(
    const float* __restrict__ gamma, const float* __restrict__ beta,
    const float* __restrict__ Wg, const float* __restrict__ bg,
    const float* __restrict__ eig_raw,
    float* io, float* __restrict__ a_buf)
{
    const int l = threadIdx.x & 63, wid = threadIdx.x >> 6;
    const long tok = (long)blockIdx.x * 4 + wid;
    float* row = io + tok * 512;
    const int c0 = l << 2;

    const float4 v0 = *(const float4*)&row[c0];
    const float4 v1 = *(const float4*)&row[c0 + 256];

    float s1 = v0.x + v0.y + v0.z + v0.w + v1.x + v1.y + v1.z + v1.w;
    float s2 = v0.x*v0.x + v0.y*v0.y + v0.z*v0.z + v0.w*v0.w
             + v1.x*v1.x + v1.y*v1.y + v1.z*v1.z + v1.w*v1.w;
    #pragma unroll
    for (int o = 32; o; o >>= 1) { s1 += __shfl_xor(s1, o, 64); s2 += __shfl_xor(s2, o, 64); }
    const float mean = s1 * (1.f/512.f);
    const float var  = s2 * (1.f/512.f) - mean*mean;
    const float rstd = 1.0f / sqrtf(var + 1e-5f);

    const float4 g0 = *(const float4*)&gamma[c0];
    const float4 g1 = *(const float4*)&gamma[c0 + 256];
    const float4 b0 = *(const float4*)&beta[c0];
    const float4 b1 = *(const float4*)&beta[c0 + 256];
    float4 xn0, xn1;
    xn0.x = (v0.x - mean)*rstd*g0.x + b0.x;  xn0.y = (v0.y - mean)*rstd*g0.y + b0.y;
    xn0.z = (v0.z - mean)*rstd*g0.z + b0.z;  xn0.w = (v0.w - mean)*rstd*g0.w + b0.w;
    xn1.x = (v1.x - mean)*rstd*g1.x + b1.x;  xn1.y = (v1.y - mean)*rstd*g1.y + b1.y;
    xn1.z = (v1.z - mean)*rstd*g1.z + b1.z;  xn1.w = (v1.w - mean)*rstd*g1.w + b1.w;

    float gt[8];
    #pragma unroll
    for (int g = 0; g < 8; ++g) {
        const float4 w0 = *(const float4*)&Wg[g * 512 + c0];
        const float4 w1 = *(const float4*)&Wg[g * 512 + c0 + 256];
        float p = xn0.x*w0.x + xn0.y*w0.y + xn0.z*w0.z + xn0.w*w0.w
                + xn1.x*w1.x + xn1.y*w1.y + xn1.z*w1.z + xn1.w*w1.w;
        #pragma unroll
        for (int o = 32; o; o >>= 1) p += __shfl_xor(p, o, 64);
        gt[g] = p + bg[g];
    }

    const int n0 = l >> 5, n1 = 2 + (l >> 5);
    const float bt0 = sigmoidf_(gt[4 + n0]);
    const float bt1 = sigmoidf_(gt[4 + n1]);
    float4 o0, o1;
    o0.x = bt0*xn0.x; o0.y = bt0*xn0.y; o0.z = bt0*xn0.z; o0.w = bt0*xn0.w;
    o1.x = bt1*xn1.x; o1.y = bt1*xn1.y; o1.z = bt1*xn1.z; o1.w = bt1*xn1.w;
    *(float4*)&row[c0]       = o0;
    *(float4*)&row[c0 + 256] = o1;

    if (l < 4) a_buf[tok * 4 + l] = tanhf(eig_raw[l]) * sigmoidf_(gt[l]);
}

// ---------------------------------------------------------------------------
// k2 (phase A): per (b, chunk): cumprod p_t -> p_buf, q=max(p,1e-6),
// B0_t = q_t * cumsum(b_tau / q_tau) in place over bvec.
// ---------------------------------------------------------------------------
__global__ __launch_bounds__(256) void k2_phaseA(
    const float* __restrict__ a_buf, float* __restrict__ p_buf,
    float* __restrict__ bvec)
{
    const int blk = blockIdx.x;
    const int b = blk >> 9, ch = blk & 511;
    const long base_s = (long)b * S_ + (long)ch * CHUNK_;
    __shared__ float qs[CHUNK_][HN_];
    const int tid = threadIdx.x;

    if (tid < HN_) {
        const int n = tid;
        float p = 1.f;
        for (int t = 0; t < CHUNK_; ++t) {
            p *= a_buf[(base_s + t) * HN_ + n];
            p_buf[(base_s + t) * HN_ + n] = p;
            qs[t][n] = fmaxf(p, 1e-6f);
        }
    }
    __syncthreads();

    #pragma unroll
    for (int cc = 0; cc < 2; ++cc) {
        const int c = tid + cc * 256;
        const int n = c >> 7;
        float s = 0.f;
        long idx = base_s * DH_ + c;
        #pragma unroll
        for (int t = 0; t < CHUNK_; ++t, idx += DH_) {
            float bb = bvec[idx];
            float q  = qs[t][n];
            s += bb / q;
            bvec[idx] = q * s;
        }
    }
}

// ---------------------------------------------------------------------------
// k3 (phase B): sequential scan over 512 chunk carries, 4096 parallel lanes.
// ---------------------------------------------------------------------------
__global__ __launch_bounds__(256) void k3_scan(
    const float* __restrict__ p_buf, const float* __restrict__ bvec,
    const float* __restrict__ h_in, float* __restrict__ h0_buf,
    float* __restrict__ h_last)
{
    const int tid = blockIdx.x * blockDim.x + threadIdx.x; // 0..4095
    const int b = tid >> 9, c = tid & 511, n = c >> 7;
    float h = h_in[b * DH_ + c];
    for (int ch = 0; ch < NC_; ++ch) {
        h0_buf[((long)(b * NC_ + ch)) * DH_ + c] = h;
        long sE = (long)b * S_ + (long)ch * CHUNK_ + (CHUNK_ - 1);
        float p15 = p_buf[sE * HN_ + n];
        float B15 = bvec[sE * DH_ + c];
        h = fmaf(p15, h, B15);
    }
    h_last[b * DH_ + c] = h;
}

extern "C" void kernel_launch(void* const* d_in, const int* in_sizes, int n_in,
                              void* d_out, int out_size, void* d_ws, size_t ws_size,
                              hipStream_t stream) {
    const float* x       = (const float*)d_in[0];
    const float* h       = (const float*)d_in[1];
    const float* Win     = (const float*)d_in[2];
    const float* gamma   = (const float*)d_in[3];
    const float* beta    = (const float*)d_in[4];
    const float* Wg      = (const float*)d_in[5];
    const float* bg      = (const float*)d_in[6];
    const float* eig_raw = (const float*)d_in[7];
    const float* Wout    = (const float*)d_in[8];

    float* out    = (float*)d_out;
    float* bvec   = out;                          // bvec -> B0 -> (h_all fused) -> out
    float* h_last = out + (long)NTOK * DH_;

    float* ws     = (float*)d_ws;
    float* a_buf  = ws;                           // 262144 f
    float* p_buf  = ws + 262144;                  // 262144 f
    float* h0_buf = ws + 524288;                  // 2097152 f
    unsigned short* WreA = (unsigned short*)(ws + 2621440); // 262144 us
    unsigned short* WreB = WreA + 262144;                   // 262144 us

    k0_convert<<<1024, 256, 0, stream>>>(Win, Wout, WreA, WreB);
    gemm_rows<false><<<NTOK/32, 256, 0, stream>>>(x, WreA, nullptr, nullptr, bvec);
    k_ln_gates<<<NTOK/4, 256, 0, stream>>>(gamma, beta, Wg, bg, eig_raw, bvec, a_buf);
    k2_phaseA<<<B_*NC_, 256, 0, stream>>>(a_buf, p_buf, bvec);
    k3_scan<<<16, 256, 0, stream>>>(p_buf, bvec, h, h0_buf, h_last);
    gemm_rows<true><<<NTOK/32, 256, 0, stream>>>(bvec, WreB, p_buf, h0_buf, bvec);
}